// Round 4
// baseline (2470.960 us; speedup 1.0000x reference)
//
#include <hip/hip_runtime.h>
#include <cstddef>

// ---------- types ----------
typedef _Float16 f16x8 __attribute__((ext_vector_type(8)));
typedef short    s16x8 __attribute__((ext_vector_type(8)));
typedef float    f32x4 __attribute__((ext_vector_type(4)));

#define MFMA_F16(a, b, c) __builtin_amdgcn_mfma_f32_16x16x32_f16((a), (b), (c), 0, 0, 0)

#if __has_builtin(__builtin_amdgcn_rcpf)
__device__ __forceinline__ float fast_rcp(float x) { return __builtin_amdgcn_rcpf(x); }
#else
__device__ __forceinline__ float fast_rcp(float x) { return 1.f / x; }
#endif

__device__ __forceinline__ f16x8 ld8(const short* p) {
  return __builtin_bit_cast(f16x8, *(const s16x8*)p);
}

// ---------- fp32 -> fp16 casts, one launch for all arrays ----------
struct CastDesc { const float* src; short* dst; int n; };
struct CastArgs { CastDesc d[7]; };

__global__ void cast_many(CastArgs a) {
  const int tid = blockIdx.x * blockDim.x + threadIdx.x;
  const int stride = gridDim.x * blockDim.x;
#pragma unroll
  for (int j = 0; j < 7; j++) {
    const float* __restrict__ s = a.d[j].src;
    short* __restrict__ o = a.d[j].dst;
    const int n = a.d[j].n;
    for (int i = tid; i < n; i += stride)
      o[i] = __builtin_bit_cast(short, (_Float16)s[i]);
  }
}

// ---------- fused GRU layer: input projection + recurrence ----------
// One wg = 16 batch rows; NW=4 waves (1 wave/SIMD, amdgpu_waves_per_eu(1,1)
// -> 512-VGPR budget); wave w owns JT 16-col j-tiles. wih fully reg-cached;
// whh k<RC reg-cached, k>=RC streamed from L2 per step (grouped loads, proj
// + cached MFMAs ordered first to cover latency). h: fp16 hi + lo(n-gate,
// prescaled 4096) double-buffered in LDS; fp32 master h in regs. XPF: x-frag
// prefetched one step ahead (covers HBM latency at 1 wave/SIMD).
template <int HIN, int H, int NW, int JT, int RC, bool XPF, bool STORE_SEQ>
__global__ __launch_bounds__(NW * 64)
__attribute__((amdgpu_waves_per_eu(1, 1)))
void gru_fused(const short* __restrict__ xin,   // [B,T,HIN] fp16 bits
               const short* __restrict__ Wih,   // [3H,HIN] fp16 bits
               const short* __restrict__ Whh,   // [3H,H] fp16 bits
               const float* __restrict__ b_ih,  // [3H]
               const float* __restrict__ b_hh,  // [3H]
               short* __restrict__ hseq,        // [B,T,H] fp16, if STORE_SEQ
               float* __restrict__ hlast) {     // [B,H] fp32, if !STORE_SEQ
  static_assert(NW * 16 * JT == H, "wave tiling must cover H");
  constexpr int T   = 256;
  constexpr int KSI = HIN / 32;
  constexpr int KS  = H / 32;
  static_assert(RC <= KS, "");
  constexpr int NS  = KS - RC;          // streamed whh k-frags per (gate,jt)
  constexpr int HP  = H + 8;            // +16B row pad, rows 16B-aligned
  __shared__ __align__(16) short hbuf[2][2][16][HP];  // [buf][hi/lo][row][col]

  const int lane = threadIdx.x & 63;
  const int wid  = threadIdx.x >> 6;
  const int p = lane & 15;
  const int q = lane >> 4;
  const int b0 = blockIdx.x * 16;
  const int j0 = wid * (16 * JT);

  for (int i = threadIdx.x; i < 2 * 16 * HP; i += NW * 64)
    (&hbuf[0][0][0][0])[i] = 0;

  // per-gate whh base for this lane's jt=0 column
  const short* whh_g[3];
#pragma unroll
  for (int g = 0; g < 3; g++)
    whh_g[g] = Whh + (size_t)(g * H + j0 + p) * H + q * 8;

  // t-invariant biases
  float brz_r[JT], brz_z[JT], bxn[JT], bhn[JT];
#pragma unroll
  for (int jt = 0; jt < JT; jt++) {
    const int col = j0 + jt * 16 + p;
    brz_r[jt] = b_ih[col] + b_hh[col];
    brz_z[jt] = b_ih[H + col] + b_hh[H + col];
    bxn[jt]   = b_ih[2 * H + col];
    bhn[jt]   = b_hh[2 * H + col];
  }

  // register-cached weight fragments (t-invariant)
  f16x8 wr_ih[JT][3][KSI];
  f16x8 wr_hh[JT][3][RC > 0 ? RC : 1];
#pragma unroll
  for (int jt = 0; jt < JT; jt++) {
    const int col = j0 + jt * 16 + p;
#pragma unroll
    for (int g = 0; g < 3; g++) {
      const short* wih_gp = Wih + (size_t)(g * H + col) * HIN + q * 8;
#pragma unroll
      for (int k = 0; k < KSI; k++) wr_ih[jt][g][k] = ld8(wih_gp + k * 32);
#pragma unroll
      for (int k = 0; k < RC; k++) wr_hh[jt][g][k] = ld8(whh_g[g] + jt * 16 * H + k * 32);
    }
  }

  float hprev[JT][4];
#pragma unroll
  for (int jt = 0; jt < JT; jt++)
#pragma unroll
    for (int r = 0; r < 4; r++) hprev[jt][r] = 0.f;

  const short* xp = xin + (size_t)(b0 + p) * T * HIN + q * 8;

  // x fragment prefetch (one step ahead when XPF)
  f16x8 axc[KSI];
#pragma unroll
  for (int k = 0; k < KSI; k++) axc[k] = ld8(xp + k * 32);

  __syncthreads();

  for (int t = 0; t < T; t++) {
    const int cur = t & 1;
    const int nxt = cur ^ 1;

    f16x8 axn[XPF ? KSI : 1];
    if (XPF) {
      // prefetch next step's x (reads 1 row past end on last wg/step: lands in
      // adjacent workspace buffer, value unused)
#pragma unroll
      for (int k = 0; k < KSI; k++) axn[k] = ld8(xp + HIN + k * 32);
    } else if (t > 0) {
#pragma unroll
      for (int k = 0; k < KSI; k++) axc[k] = ld8(xp + k * 32);
    }

    // h_{t-1} fragments from LDS
    f16x8 ah[KS], al[KS];
#pragma unroll
    for (int k = 0; k < KS; k++) {
      ah[k] = ld8(&hbuf[cur][0][p][k * 32 + q * 8]);
      al[k] = ld8(&hbuf[cur][1][p][k * 32 + q * 8]);
    }

#pragma unroll
    for (int jt = 0; jt < JT; jt++) {
      // issue this jt's streamed whh loads first (consumed after cached MFMAs)
      f16x8 st[3][NS > 0 ? NS : 1];
      if (NS > 0) {
#pragma unroll
        for (int g = 0; g < 3; g++)
#pragma unroll
          for (int k = 0; k < NS; k++)
            st[g][k] = ld8(whh_g[g] + jt * 16 * H + (RC + k) * 32);
      }

      f32x4 ar = {0.f, 0.f, 0.f, 0.f};
      f32x4 az = {0.f, 0.f, 0.f, 0.f};
      f32x4 xn = {0.f, 0.f, 0.f, 0.f};
      f32x4 an = {0.f, 0.f, 0.f, 0.f};
      f32x4 ln = {0.f, 0.f, 0.f, 0.f};

      // input projection (all cached) — runs while streamed loads in flight
#pragma unroll
      for (int k = 0; k < KSI; k++) {
        ar = MFMA_F16(axc[k], wr_ih[jt][0][k], ar);
        az = MFMA_F16(axc[k], wr_ih[jt][1][k], az);
        xn = MFMA_F16(axc[k], wr_ih[jt][2][k], xn);
      }
      // recurrence, cached k
#pragma unroll
      for (int k = 0; k < RC; k++) {
        ar = MFMA_F16(ah[k], wr_hh[jt][0][k], ar);
        az = MFMA_F16(ah[k], wr_hh[jt][1][k], az);
        an = MFMA_F16(ah[k], wr_hh[jt][2][k], an);
        ln = MFMA_F16(al[k], wr_hh[jt][2][k], ln);
      }
      // recurrence, streamed k
      if (NS > 0) {
#pragma unroll
        for (int k = 0; k < NS; k++) {
          ar = MFMA_F16(ah[RC + k], st[0][k], ar);
          az = MFMA_F16(ah[RC + k], st[1][k], az);
          an = MFMA_F16(ah[RC + k], st[2][k], an);
          ln = MFMA_F16(al[RC + k], st[2][k], ln);
        }
      }

      // epilogue: C/D layout col = lane&15, row = q*4+r (batch)
      constexpr float LS = 1.f / 4096.f;
#pragma unroll
      for (int r = 0; r < 4; r++) {
        const int bm = q * 4 + r;
        const int col = j0 + jt * 16 + p;
        const float rpre = ar[r] + brz_r[jt];
        const float zpre = az[r] + brz_z[jt];
        const float ghn  = an[r] + ln[r] * LS + bhn[jt];
        const float rg = fast_rcp(1.f + __expf(-rpre));
        const float zg = fast_rcp(1.f + __expf(-zpre));
        const float narg = xn[r] + bxn[jt] + rg * ghn;
        const float e2 = __expf(2.f * narg);
        const float ng = 1.f - 2.f * fast_rcp(e2 + 1.f);  // tanh(narg)
        const float hnew = (1.f - zg) * ng + zg * hprev[jt][r];
        hprev[jt][r] = hnew;
        const _Float16 hi = (_Float16)hnew;
        const _Float16 lo = (_Float16)((hnew - (float)hi) * 4096.f);
        hbuf[nxt][0][bm][col] = __builtin_bit_cast(short, hi);
        hbuf[nxt][1][bm][col] = __builtin_bit_cast(short, lo);
        if (STORE_SEQ) {
          hseq[((size_t)(b0 + bm) * T + t) * H + col] = __builtin_bit_cast(short, hi);
        } else if (t == T - 1) {
          hlast[(size_t)(b0 + bm) * H + col] = hnew;
        }
      }
    }
    if (XPF) {
#pragma unroll
      for (int k = 0; k < KSI; k++) axc[k] = axn[k];
    }
    xp += HIN;
    __syncthreads();  // h writes (nxt) visible before next step's reads
  }
}

// ---------- dense head: out[b] = dot(hlast[b,:], Wd) + bd ----------
__global__ void dense_kernel(const float* __restrict__ hl, const float* __restrict__ Wd,
                             const float* __restrict__ bd, float* __restrict__ out) {
  const int b = blockIdx.x * 64 + threadIdx.x;
  float a = bd[0];
#pragma unroll
  for (int k = 0; k < 64; k++) a = fmaf(hl[b * 64 + k], Wd[k], a);
  out[b] = a;
}

// ---------- host ----------
extern "C" void kernel_launch(void* const* d_in, const int* in_sizes, int n_in,
                              void* d_out, int out_size, void* d_ws, size_t ws_size,
                              hipStream_t stream) {
  constexpr int B = 512, T = 256, F = 64;
  constexpr int H1 = 256, H2 = 128, H3 = 64;
  constexpr int M = B * T;

  const float* x     = (const float*)d_in[0];
  const float* W_ih1 = (const float*)d_in[1];
  const float* W_hh1 = (const float*)d_in[2];
  const float* b_ih1 = (const float*)d_in[3];
  const float* b_hh1 = (const float*)d_in[4];
  const float* W_ih2 = (const float*)d_in[5];
  const float* W_hh2 = (const float*)d_in[6];
  const float* b_ih2 = (const float*)d_in[7];
  const float* b_hh2 = (const float*)d_in[8];
  const float* W_ih3 = (const float*)d_in[9];
  const float* W_hh3 = (const float*)d_in[10];
  const float* b_ih3 = (const float*)d_in[11];
  const float* b_hh3 = (const float*)d_in[12];
  const float* W_d   = (const float*)d_in[13];
  const float* b_d   = (const float*)d_in[14];
  float* out = (float*)d_out;

  char* ws = (char*)d_ws;
  size_t off = 0;
  auto alloc = [&](size_t bytes) -> char* {
    char* pp = ws + off;
    off = (off + bytes + 255) & ~(size_t)255;
    return pp;
  };

  const int nx    = M * F;
  const int nwih1 = 3 * H1 * F,  nwhh1 = 3 * H1 * H1;
  const int nwih2 = 3 * H2 * H1, nwhh2 = 3 * H2 * H2;
  const int nwih3 = 3 * H3 * H2, nwhh3 = 3 * H3 * H3;

  short* xh    = (short*)alloc((size_t)nx * 2);
  short* wih1  = (short*)alloc((size_t)nwih1 * 2);
  short* whh1  = (short*)alloc((size_t)nwhh1 * 2);
  short* wih2  = (short*)alloc((size_t)nwih2 * 2);
  short* whh2  = (short*)alloc((size_t)nwhh2 * 2);
  short* wih3  = (short*)alloc((size_t)nwih3 * 2);
  short* whh3  = (short*)alloc((size_t)nwhh3 * 2);
  short* h1    = (short*)alloc((size_t)M * H1 * 2);
  short* h2    = (short*)alloc((size_t)M * H2 * 2);
  float* hlast = (float*)alloc((size_t)B * H3 * 4);
  (void)ws_size; (void)n_in; (void)in_sizes; (void)out_size;

  // all casts in one launch
  CastArgs ca;
  ca.d[0] = {x, xh, nx};
  ca.d[1] = {W_ih1, wih1, nwih1};
  ca.d[2] = {W_hh1, whh1, nwhh1};
  ca.d[3] = {W_ih2, wih2, nwih2};
  ca.d[4] = {W_hh2, whh2, nwhh2};
  ca.d[5] = {W_ih3, wih3, nwih3};
  ca.d[6] = {W_hh3, whh3, nwhh3};
  cast_many<<<1024, 256, 0, stream>>>(ca);

  // fused layers: 32 wgs, NW=4 waves (1 wave/SIMD, 512-VGPR budget)
  // template: HIN, H, NW, JT, RC(whh k-frags reg-cached), XPF, STORE_SEQ
  // L1: wih cached, whh 5/8 cached -> stream 36 KB/wave/step
  gru_fused<64, 256, 4, 4, 5, false, true><<<B / 16, 4 * 64, 0, stream>>>(
      xh, wih1, whh1, b_ih1, b_hh1, h1, nullptr);
  // L2: everything register-resident, zero per-step weight streaming
  gru_fused<256, 128, 4, 2, 4, true, true><<<B / 16, 4 * 64, 0, stream>>>(
      h1, wih2, whh2, b_ih2, b_hh2, h2, nullptr);
  // L3: everything register-resident
  gru_fused<128, 64, 4, 1, 2, true, false><<<B / 16, 4 * 64, 0, stream>>>(
      h2, wih3, whh3, b_ih3, b_hh3, nullptr, hlast);

  dense_kernel<<<B / 64, 64, 0, stream>>>(hlast, W_d, b_d, out);
}

// Round 5
// 1452.313 us; speedup vs baseline: 1.7014x; 1.7014x over previous
//
#include <hip/hip_runtime.h>
#include <cstddef>

// ---------- types ----------
typedef _Float16 f16x8 __attribute__((ext_vector_type(8)));
typedef short    s16x8 __attribute__((ext_vector_type(8)));
typedef float    f32x4 __attribute__((ext_vector_type(4)));

#define MFMA_F16(a, b, c) __builtin_amdgcn_mfma_f32_16x16x32_f16((a), (b), (c), 0, 0, 0)

#if __has_builtin(__builtin_amdgcn_rcpf)
__device__ __forceinline__ float fast_rcp(float x) { return __builtin_amdgcn_rcpf(x); }
#else
__device__ __forceinline__ float fast_rcp(float x) { return 1.f / x; }
#endif

__device__ __forceinline__ f16x8 ld8(const short* p) {
  return __builtin_bit_cast(f16x8, *(const s16x8*)p);
}

// ---------- fp32 -> fp16 casts, one launch ----------
struct CastDesc { const float* src; short* dst; int n; };
struct CastArgs { CastDesc d[7]; };

__global__ void cast_many(CastArgs a) {
  const int tid = blockIdx.x * blockDim.x + threadIdx.x;
  const int stride = gridDim.x * blockDim.x;
#pragma unroll
  for (int j = 0; j < 7; j++) {
    const float* __restrict__ s = a.d[j].src;
    short* __restrict__ o = a.d[j].dst;
    const int n = a.d[j].n;
    for (int i = tid; i < n; i += stride)
      o[i] = __builtin_bit_cast(short, (_Float16)s[i]);
  }
}

// ---------- fused GRU layer ----------
// One wg = 16 batch rows, NW waves; wave w owns JT 16-col j-tiles.
// ZERO per-step global weight traffic:
//   WLDS==1 (L1): whh_n in LDS, whh_r/z + wih register-resident.
//   WLDS==3 (L2/L3): whole whh in LDS, wih register-resident.
// h stored fp16 single-plane, double-buffered in LDS (1 barrier/step).
// Rec loop (LDS) runs before proj loop so the per-step x load latency hides.
template <int HIN, int H, int NW, int JT, int WLDS, bool XPF, bool STORE_SEQ>
__global__ __launch_bounds__(NW * 64)
__attribute__((amdgpu_waves_per_eu(NW / 4, NW / 4)))
void gru_fused(const short* __restrict__ xin,   // [B,T,HIN] fp16 bits
               const short* __restrict__ Wih,   // [3H,HIN] fp16 bits
               const short* __restrict__ Whh,   // [3H,H] fp16 bits
               const float* __restrict__ b_ih,  // [3H]
               const float* __restrict__ b_hh,  // [3H]
               short* __restrict__ hseq,        // [B,T,H] fp16, if STORE_SEQ
               float* __restrict__ hlast) {     // [B,H] fp32, if !STORE_SEQ
  static_assert(NW * 16 * JT == H, "wave tiling must cover H");
  constexpr int T   = 256;
  constexpr int KSI = HIN / 32;
  constexpr int KS  = H / 32;
  constexpr int HP  = H + 8;        // +16B row pad: uniform bank spread
  constexpr int WROWS = WLDS * H;   // weight rows resident in LDS

  extern __shared__ __align__(16) short smem[];
  short* whhL = smem;                  // [WROWS][HP]
  short* hb   = smem + WROWS * HP;     // [2][16][HP] (double-buffered h)

  const int tid  = threadIdx.x;
  const int lane = tid & 63;
  const int wid  = tid >> 6;
  const int p = lane & 15;
  const int q = lane >> 4;
  const int b0 = blockIdx.x * 16;
  const int j0 = wid * (16 * JT);

  // init h buffers to 0
  for (int i = tid; i < 2 * 16 * HP; i += NW * 64) hb[i] = 0;

  // stage whh gate rows into LDS (one-time)
  constexpr int GOFF = (WLDS == 1) ? 2 * H : 0;  // L1: n-gate rows only
  constexpr int KV = H / 8;
  for (int i = tid; i < WROWS * KV; i += NW * 64) {
    const int row = i / KV, kc = i - row * KV;
    *(s16x8*)&whhL[row * HP + kc * 8] =
        *(const s16x8*)&Whh[(size_t)(GOFF + row) * H + kc * 8];
  }

  // t-invariant biases + LDS row ids
  float brz_r[JT], brz_z[JT], bxn[JT], bhn[JT];
  int wrow[JT];
#pragma unroll
  for (int jt = 0; jt < JT; jt++) {
    const int col = j0 + jt * 16 + p;
    brz_r[jt] = b_ih[col] + b_hh[col];
    brz_z[jt] = b_ih[H + col] + b_hh[H + col];
    bxn[jt]   = b_ih[2 * H + col];
    bhn[jt]   = b_hh[2 * H + col];
    wrow[jt]  = col;
  }

  // register-resident weights
  f16x8 wr_ih[JT][3][KSI];
#pragma unroll
  for (int jt = 0; jt < JT; jt++) {
    const int col = j0 + jt * 16 + p;
#pragma unroll
    for (int g = 0; g < 3; g++) {
      const short* src = Wih + (size_t)(g * H + col) * HIN + q * 8;
#pragma unroll
      for (int k = 0; k < KSI; k++) wr_ih[jt][g][k] = ld8(src + k * 32);
    }
  }
  f16x8 wr_hh[(WLDS == 1) ? JT : 1][2][(WLDS == 1) ? KS : 1];
  if constexpr (WLDS == 1) {
#pragma unroll
    for (int jt = 0; jt < JT; jt++) {
      const int col = j0 + jt * 16 + p;
#pragma unroll
      for (int g = 0; g < 2; g++) {  // r, z
        const short* src = Whh + (size_t)(g * H + col) * H + q * 8;
#pragma unroll
        for (int k = 0; k < KS; k++) wr_hh[jt][g][k] = ld8(src + k * 32);
      }
    }
  }

  float hprev[JT][4];
#pragma unroll
  for (int jt = 0; jt < JT; jt++)
#pragma unroll
    for (int r = 0; r < 4; r++) hprev[jt][r] = 0.f;

  const short* xp = xin + (size_t)(b0 + p) * T * HIN + q * 8;

  f16x8 axc[KSI];
  if constexpr (XPF) {  // prime the cross-step x prefetch
#pragma unroll
    for (int k = 0; k < KSI; k++) axc[k] = ld8(xp + k * 32);
  }

  __syncthreads();

  for (int t = 0; t < T; t++) {
    const int cur = t & 1;
    short* hbc = hb + cur * 16 * HP;
    short* hbn = hb + (cur ^ 1) * 16 * HP;

    f16x8 axn_[XPF ? KSI : 1];
    if constexpr (XPF) {
      // next step's x; last-step overrun stays inside the workspace
#pragma unroll
      for (int k = 0; k < KSI; k++) axn_[k] = ld8(xp + HIN + k * 32);
    } else {
      // this step's x; issued now, consumed after the rec loop (latency hidden)
#pragma unroll
      for (int k = 0; k < KSI; k++) axc[k] = ld8(xp + k * 32);
    }

    f32x4 ar[JT], az[JT], xn[JT], an[JT];
#pragma unroll
    for (int jt = 0; jt < JT; jt++) {
      ar[jt] = f32x4{0.f, 0.f, 0.f, 0.f};
      az[jt] = f32x4{0.f, 0.f, 0.f, 0.f};
      xn[jt] = f32x4{0.f, 0.f, 0.f, 0.f};
      an[jt] = f32x4{0.f, 0.f, 0.f, 0.f};
    }

    // recurrence: k outer (h frag read once, shared across jt)
#pragma unroll
    for (int k = 0; k < KS; k++) {
      const f16x8 ahk = ld8(&hbc[p * HP + k * 32 + q * 8]);
#pragma unroll
      for (int jt = 0; jt < JT; jt++) {
        if constexpr (WLDS == 1) {
          ar[jt] = MFMA_F16(ahk, wr_hh[jt][0][k], ar[jt]);
          az[jt] = MFMA_F16(ahk, wr_hh[jt][1][k], az[jt]);
          const f16x8 wnk = ld8(&whhL[wrow[jt] * HP + k * 32 + q * 8]);
          an[jt] = MFMA_F16(ahk, wnk, an[jt]);
        } else {
          const f16x8 wrk = ld8(&whhL[(0 * H + wrow[jt]) * HP + k * 32 + q * 8]);
          const f16x8 wzk = ld8(&whhL[(1 * H + wrow[jt]) * HP + k * 32 + q * 8]);
          const f16x8 wnk = ld8(&whhL[(2 * H + wrow[jt]) * HP + k * 32 + q * 8]);
          ar[jt] = MFMA_F16(ahk, wrk, ar[jt]);
          az[jt] = MFMA_F16(ahk, wzk, az[jt]);
          an[jt] = MFMA_F16(ahk, wnk, an[jt]);
        }
      }
    }
    // input projection (registers only)
#pragma unroll
    for (int k = 0; k < KSI; k++) {
#pragma unroll
      for (int jt = 0; jt < JT; jt++) {
        ar[jt] = MFMA_F16(axc[k], wr_ih[jt][0][k], ar[jt]);
        az[jt] = MFMA_F16(axc[k], wr_ih[jt][1][k], az[jt]);
        xn[jt] = MFMA_F16(axc[k], wr_ih[jt][2][k], xn[jt]);
      }
    }

    // epilogue: C/D layout col = lane&15, row = q*4+r
#pragma unroll
    for (int jt = 0; jt < JT; jt++) {
#pragma unroll
      for (int r = 0; r < 4; r++) {
        const int bm = q * 4 + r;
        const int col = j0 + jt * 16 + p;
        const float rpre = ar[jt][r] + brz_r[jt];
        const float zpre = az[jt][r] + brz_z[jt];
        const float ghn  = an[jt][r] + bhn[jt];
        const float rg = fast_rcp(1.f + __expf(-rpre));
        const float zg = fast_rcp(1.f + __expf(-zpre));
        const float narg = xn[jt][r] + bxn[jt] + rg * ghn;
        const float e2 = __expf(2.f * narg);
        const float ng = 1.f - 2.f * fast_rcp(e2 + 1.f);  // tanh
        const float hnew = (1.f - zg) * ng + zg * hprev[jt][r];
        hprev[jt][r] = hnew;
        const _Float16 hf = (_Float16)hnew;
        hbn[bm * HP + col] = __builtin_bit_cast(short, hf);
        if (STORE_SEQ) {
          hseq[((size_t)(b0 + bm) * T + t) * H + col] = __builtin_bit_cast(short, hf);
        } else if (t == T - 1) {
          hlast[(size_t)(b0 + bm) * H + col] = hnew;
        }
      }
    }
    if constexpr (XPF) {
#pragma unroll
      for (int k = 0; k < KSI; k++) axc[k] = axn_[k];
    }
    xp += HIN;
    __syncthreads();
  }
}

// ---------- dense head ----------
__global__ void dense_kernel(const float* __restrict__ hl, const float* __restrict__ Wd,
                             const float* __restrict__ bd, float* __restrict__ out) {
  const int b = blockIdx.x * 64 + threadIdx.x;
  float a = bd[0];
#pragma unroll
  for (int k = 0; k < 64; k++) a = fmaf(hl[b * 64 + k], Wd[k], a);
  out[b] = a;
}

// ---------- host ----------
extern "C" void kernel_launch(void* const* d_in, const int* in_sizes, int n_in,
                              void* d_out, int out_size, void* d_ws, size_t ws_size,
                              hipStream_t stream) {
  constexpr int B = 512, T = 256, F = 64;
  constexpr int H1 = 256, H2 = 128, H3 = 64;
  constexpr int M = B * T;

  const float* x     = (const float*)d_in[0];
  const float* W_ih1 = (const float*)d_in[1];
  const float* W_hh1 = (const float*)d_in[2];
  const float* b_ih1 = (const float*)d_in[3];
  const float* b_hh1 = (const float*)d_in[4];
  const float* W_ih2 = (const float*)d_in[5];
  const float* W_hh2 = (const float*)d_in[6];
  const float* b_ih2 = (const float*)d_in[7];
  const float* b_hh2 = (const float*)d_in[8];
  const float* W_ih3 = (const float*)d_in[9];
  const float* W_hh3 = (const float*)d_in[10];
  const float* b_ih3 = (const float*)d_in[11];
  const float* b_hh3 = (const float*)d_in[12];
  const float* W_d   = (const float*)d_in[13];
  const float* b_d   = (const float*)d_in[14];
  float* out = (float*)d_out;

  char* ws = (char*)d_ws;
  size_t off = 0;
  auto alloc = [&](size_t bytes) -> char* {
    char* pp = ws + off;
    off = (off + bytes + 255) & ~(size_t)255;
    return pp;
  };

  const int nx    = M * F;
  const int nwih1 = 3 * H1 * F,  nwhh1 = 3 * H1 * H1;
  const int nwih2 = 3 * H2 * H1, nwhh2 = 3 * H2 * H2;
  const int nwih3 = 3 * H3 * H2, nwhh3 = 3 * H3 * H3;

  short* xh    = (short*)alloc((size_t)nx * 2);
  short* wih1  = (short*)alloc((size_t)nwih1 * 2);
  short* whh1  = (short*)alloc((size_t)nwhh1 * 2);
  short* wih2  = (short*)alloc((size_t)nwih2 * 2);
  short* whh2  = (short*)alloc((size_t)nwhh2 * 2);
  short* wih3  = (short*)alloc((size_t)nwih3 * 2);
  short* whh3  = (short*)alloc((size_t)nwhh3 * 2);
  short* h1    = (short*)alloc((size_t)M * H1 * 2);
  short* h2    = (short*)alloc((size_t)M * H2 * 2);
  float* hlast = (float*)alloc((size_t)B * H3 * 4);
  (void)ws_size; (void)n_in; (void)in_sizes; (void)out_size;

  CastArgs ca;
  ca.d[0] = {x, xh, nx};
  ca.d[1] = {W_ih1, wih1, nwih1};
  ca.d[2] = {W_hh1, whh1, nwhh1};
  ca.d[3] = {W_ih2, wih2, nwih2};
  ca.d[4] = {W_hh2, whh2, nwhh2};
  ca.d[5] = {W_ih3, wih3, nwih3};
  ca.d[6] = {W_hh3, whh3, nwhh3};
  cast_many<<<1024, 256, 0, stream>>>(ca);

  // dynamic LDS sizes: (WLDS*H + 2*16) * (H+8) * 2 bytes
  constexpr int SM1 = (1 * H1 + 32) * (H1 + 8) * 2;  // 152064
  constexpr int SM2 = (3 * H2 + 32) * (H2 + 8) * 2;  // 113152
  constexpr int SM3 = (3 * H3 + 32) * (H3 + 8) * 2;  //  32256

  auto* k1 = gru_fused<64, 256, 8, 2, 1, false, true>;
  auto* k2 = gru_fused<256, 128, 8, 1, 3, true, true>;
  auto* k3 = gru_fused<128, 64, 4, 1, 3, true, false>;
  // opt-in for >64KB dynamic LDS (ignore errors; no-op where unsupported)
  (void)hipFuncSetAttribute((const void*)k1, hipFuncAttributeMaxDynamicSharedMemorySize, SM1);
  (void)hipFuncSetAttribute((const void*)k2, hipFuncAttributeMaxDynamicSharedMemorySize, SM2);
  (void)hipFuncSetAttribute((const void*)k3, hipFuncAttributeMaxDynamicSharedMemorySize, SM3);

  k1<<<B / 16, 8 * 64, SM1, stream>>>(xh, wih1, whh1, b_ih1, b_hh1, h1, nullptr);
  k2<<<B / 16, 8 * 64, SM2, stream>>>(h1, wih2, whh2, b_ih2, b_hh2, h2, nullptr);
  k3<<<B / 16, 4 * 64, SM3, stream>>>(h2, wih3, whh3, b_ih3, b_hh3, nullptr, hlast);

  dense_kernel<<<B / 64, 64, 0, stream>>>(hlast, W_d, b_d, out);
}